// Round 1
// baseline (90.857 us; speedup 1.0000x reference)
//
#include <hip/hip_runtime.h>

#define BB  256
#define LL  512
#define DD  64
#define NID 10000
#define NW  (NID / 2)   // packed u16 pairs per histogram

// Kernel A: T[a][e] = sum_d relu(a*W1[d]+b1[d]) * W2[e][d] + b2[e],  a in [0,512]
__global__ void build_table(const float* __restrict__ W1, const float* __restrict__ b1,
                            const float* __restrict__ W2, const float* __restrict__ b2,
                            float* __restrict__ T) {
    int a = blockIdx.x;    // 0..512
    int e = threadIdx.x;   // 0..63
    __shared__ float h[DD];
    h[e] = fmaxf((float)a * W1[e] + b1[e], 0.0f);
    __syncthreads();
    const float* w2row = W2 + e * DD;
    float acc = b2[e];
#pragma unroll
    for (int d = 0; d < DD; ++d) acc += h[d] * w2row[d];
    T[a * DD + e] = acc;
}

// Kernel B: per-batch histograms -> counts -> table gather -> stream output
__global__ __launch_bounds__(512) void count_encode(
    const int* __restrict__ src_ids, const int* __restrict__ dst_ids,
    const float* __restrict__ T, float* __restrict__ out)
{
    __shared__ unsigned int hs[NW];          // src histogram, 2 u16 per word
    __shared__ unsigned int hd[NW];          // dst histogram
    __shared__ int sids[LL];
    __shared__ int dids[LL];
    __shared__ unsigned short as0[LL], as1[LL], ad0[LL], ad1[LL];

    const int t = threadIdx.x;
    const int b = blockIdx.x;

    // zero histograms (~10 iters/thread each)
    for (int i = t; i < NW; i += 512) { hs[i] = 0u; hd[i] = 0u; }
    sids[t] = src_ids[b * LL + t];
    dids[t] = dst_ids[b * LL + t];
    __syncthreads();

    const int sid = sids[t];
    const int did = dids[t];
    atomicAdd(&hs[sid >> 1], 1u << ((sid & 1) * 16));
    atomicAdd(&hd[did >> 1], 1u << ((did & 1) * 16));
    __syncthreads();

    unsigned int c_ss = (hs[sid >> 1] >> ((sid & 1) * 16)) & 0xFFFFu;
    unsigned int c_sd = (hd[sid >> 1] >> ((sid & 1) * 16)) & 0xFFFFu;
    unsigned int c_ds = (hs[did >> 1] >> ((did & 1) * 16)) & 0xFFFFu;
    unsigned int c_dd = (hd[did >> 1] >> ((did & 1) * 16)) & 0xFFFFu;
    if (sid == 0) { c_ss = 0u; c_sd = 0u; }   // padding mask (app -> 0.0; T[0] is f(0))
    if (did == 0) { c_ds = 0u; c_dd = 0u; }
    as0[t] = (unsigned short)c_ss;
    as1[t] = (unsigned short)c_sd;
    ad0[t] = (unsigned short)c_ds;
    ad1[t] = (unsigned short)c_dd;
    __syncthreads();

    // Output: feat[b,l,:] = T[a0] + T[a1], float4-vectorized.
    // 512 threads = 32 rows/pass (16 float4 per 64-float row), 16 passes.
    const float4* T4      = (const float4*)T;
    float4* out_src = (float4*)(out + (size_t)b * LL * DD);
    float4* out_dst = (float4*)(out + (size_t)BB * LL * DD + (size_t)b * LL * DD);
    const int q     = t & 15;   // float4 slot within row
    const int lbase = t >> 4;   // 0..31

#pragma unroll 4
    for (int pass = 0; pass < 16; ++pass) {
        const int l = pass * 32 + lbase;
        const float4 s0 = T4[(int)as0[l] * 16 + q];
        const float4 s1 = T4[(int)as1[l] * 16 + q];
        float4 v;
        v.x = s0.x + s1.x; v.y = s0.y + s1.y; v.z = s0.z + s1.z; v.w = s0.w + s1.w;
        out_src[l * 16 + q] = v;
        const float4 d0 = T4[(int)ad0[l] * 16 + q];
        const float4 d1 = T4[(int)ad1[l] * 16 + q];
        float4 w;
        w.x = d0.x + d1.x; w.y = d0.y + d1.y; w.z = d0.z + d1.z; w.w = d0.w + d1.w;
        out_dst[l * 16 + q] = w;
    }
}

extern "C" void kernel_launch(void* const* d_in, const int* in_sizes, int n_in,
                              void* d_out, int out_size, void* d_ws, size_t ws_size,
                              hipStream_t stream) {
    const int*   src_ids = (const int*)d_in[0];
    const int*   dst_ids = (const int*)d_in[1];
    const float* W1      = (const float*)d_in[2];   // (64,1)
    const float* b1      = (const float*)d_in[3];   // (64,)
    const float* W2      = (const float*)d_in[4];   // (64,64)
    const float* b2      = (const float*)d_in[5];   // (64,)
    float* out = (float*)d_out;
    float* T   = (float*)d_ws;                      // 513*64*4 = 131,328 B

    build_table<<<dim3(LL + 1), dim3(DD), 0, stream>>>(W1, b1, W2, b2, T);
    count_encode<<<dim3(BB), dim3(512), 0, stream>>>(src_ids, dst_ids, T, out);
}